// Round 1
// baseline (17.679 us; speedup 1.0000x reference)
//
#include <hip/hip_runtime.h>
#include <math.h>

#define Bsz 4096
#define Dd 32
#define Hh 256
#define ROWS 16
#define INTEGRAL_C 1.0f

// Layout strides (in floats). Chosen so float4 (16B) accesses stay 16B-aligned
// (stride*4 % 16 == 0) and rows map to distinct bank-quads (stride/4 odd mod 8).
#define W2_STRIDE 36   // W2s[j][i], j<256, i<32
#define Z_STRIDE 36    // zs[r][d]
#define H_STRIDE 260   // hbuf[r][j]

__global__ __launch_bounds__(256) void ffjord_fused(
    const float* __restrict__ t,
    const float* __restrict__ z,
    const float* __restrict__ W1,
    const float* __restrict__ b1,
    const float* __restrict__ W2,
    const float* __restrict__ b2,
    float* __restrict__ f_out,
    float* __restrict__ dlogp_out)
{
    __shared__ float W2s[Hh * W2_STRIDE];      // 36 KB
    __shared__ float zs[ROWS * Z_STRIDE];      // 2.25 KB
    __shared__ float hbuf[ROWS * H_STRIDE];    // 16.25 KB
    __shared__ float4 psum[128 * 2];           // 4 KB
    __shared__ float tpart[ROWS][4];

    const int tid = threadIdx.x;
    const int row0 = blockIdx.x * ROWS;

    // ---- stage W2 [H][D] -> LDS padded, coalesced global reads ----
    for (int idx = tid; idx < Hh * Dd; idx += 256) {
        const int j = idx >> 5, i = idx & 31;
        W2s[j * W2_STRIDE + i] = W2[idx];
    }
    // ---- stage this block's 16 z rows ----
    for (int idx = tid; idx < ROWS * Dd; idx += 256) {
        const int r = idx >> 5, d = idx & 31;
        zs[r * Z_STRIDE + d] = z[row0 * Dd + idx];
    }

    // ---- W1 column j (z-part) into registers: one-time coalesced loads ----
    float w1r[Dd];
#pragma unroll
    for (int d = 0; d < Dd; ++d)
        w1r[d] = W1[(1 + d) * Hh + tid];

    const float tval = t[0];
    const float scale = 1.0f / sqrtf(1.0f - expf(-(INTEGRAL_C * tval * tval)));
    const float coef = -INTEGRAL_C * tval;          // f = coef*(z - scale*out)
    const float ubase = b1[tid] + tval * W1[tid];   // t * W1[0][j] + b1[j]

    __syncthreads();

    // ---- c_j = sum_d W1[1+d][j] * W2[j][d]  (trace weight per hidden unit) ----
    float c = 0.0f;
#pragma unroll
    for (int d4 = 0; d4 < 8; ++d4) {
        const float4 w2v = *(const float4*)&W2s[tid * W2_STRIDE + d4 * 4];
        c += w1r[4 * d4 + 0] * w2v.x + w1r[4 * d4 + 1] * w2v.y +
             w1r[4 * d4 + 2] * w2v.z + w1r[4 * d4 + 3] * w2v.w;
    }

    // ---- phase 1: h for all 16 rows; per-row trace partial T ----
    for (int r = 0; r < ROWS; ++r) {
        float u = ubase;
#pragma unroll
        for (int d4 = 0; d4 < 8; ++d4) {
            const float4 zv = *(const float4*)&zs[r * Z_STRIDE + d4 * 4];  // broadcast
            u += w1r[4 * d4 + 0] * zv.x + w1r[4 * d4 + 1] * zv.y +
                 w1r[4 * d4 + 2] * zv.z + w1r[4 * d4 + 3] * zv.w;
        }
        const float h = tanhf(u);
        hbuf[r * H_STRIDE + tid] = h;
        float g = (1.0f - h * h) * c;
#pragma unroll
        for (int off = 32; off > 0; off >>= 1)
            g += __shfl_xor(g, off, 64);
        if ((tid & 63) == 0) tpart[r][tid >> 6] = g;   // one partial per wave
    }
    __syncthreads();

    // ---- phase 2: out = h @ W2, register-blocked 1 row x 4 cols, j split in halves ----
    {
        const int i4 = tid & 7;            // column group: i = 4*i4 .. +3
        const int r = (tid >> 3) & 15;     // row within block
        const int jh = tid >> 7;           // which half of j-range
        float4 acc;
        acc.x = acc.y = acc.z = acc.w = 0.0f;
        const int j0 = jh * 128;
#pragma unroll 4
        for (int j = j0; j < j0 + 128; j += 4) {
            const float4 h4 = *(const float4*)&hbuf[r * H_STRIDE + j];
            const float4 wv0 = *(const float4*)&W2s[(j + 0) * W2_STRIDE + i4 * 4];
            const float4 wv1 = *(const float4*)&W2s[(j + 1) * W2_STRIDE + i4 * 4];
            const float4 wv2 = *(const float4*)&W2s[(j + 2) * W2_STRIDE + i4 * 4];
            const float4 wv3 = *(const float4*)&W2s[(j + 3) * W2_STRIDE + i4 * 4];
            acc.x += h4.x * wv0.x + h4.y * wv1.x + h4.z * wv2.x + h4.w * wv3.x;
            acc.y += h4.x * wv0.y + h4.y * wv1.y + h4.z * wv2.y + h4.w * wv3.y;
            acc.z += h4.x * wv0.z + h4.y * wv1.z + h4.z * wv2.z + h4.w * wv3.z;
            acc.w += h4.x * wv0.w + h4.y * wv1.w + h4.z * wv2.w + h4.w * wv3.w;
        }
        psum[(tid & 127) * 2 + jh] = acc;
    }
    __syncthreads();

    // ---- combine + epilogue: f = coef*(z - scale*(out+b2)) ----
    if (tid < 128) {
        const int i4 = tid & 7;
        const int r = tid >> 3;
        const float4 p0 = psum[tid * 2 + 0];
        const float4 p1 = psum[tid * 2 + 1];
        const float4 b2v = *(const float4*)&b2[i4 * 4];
        const float4 zv = *(const float4*)&zs[r * Z_STRIDE + i4 * 4];
        float4 o;
        o.x = coef * (zv.x - scale * (p0.x + p1.x + b2v.x));
        o.y = coef * (zv.y - scale * (p0.y + p1.y + b2v.y));
        o.z = coef * (zv.z - scale * (p0.z + p1.z + b2v.z));
        o.w = coef * (zv.w - scale * (p0.w + p1.w + b2v.w));
        *(float4*)&f_out[(row0 + r) * Dd + i4 * 4] = o;
    }
    // ---- finish trace: dlogp = INTEGRAL*t*(D - scale*T) ----
    if (tid < 64) {
        const int r = tid >> 2, w = tid & 3;
        float v = tpart[r][w];
        v += __shfl_xor(v, 1, 64);
        v += __shfl_xor(v, 2, 64);
        if (w == 0)
            dlogp_out[row0 + r] = INTEGRAL_C * tval * ((float)Dd - scale * v);
    }
}

extern "C" void kernel_launch(void* const* d_in, const int* in_sizes, int n_in,
                              void* d_out, int out_size, void* d_ws, size_t ws_size,
                              hipStream_t stream) {
    const float* t  = (const float*)d_in[0];
    const float* z  = (const float*)d_in[1];
    const float* W1 = (const float*)d_in[2];
    const float* b1 = (const float*)d_in[3];
    const float* W2 = (const float*)d_in[4];
    const float* b2 = (const float*)d_in[5];
    float* f_out = (float*)d_out;
    float* dlogp_out = f_out + Bsz * Dd;

    ffjord_fused<<<Bsz / ROWS, 256, 0, stream>>>(t, z, W1, b1, W2, b2, f_out, dlogp_out);
}

// Round 2
// 15.344 us; speedup vs baseline: 1.1522x; 1.1522x over previous
//
#include <hip/hip_runtime.h>
#include <math.h>

#define Bsz 4096
#define Dd 32
#define Hh 256
#define ROWS 4
#define NBLK (Bsz / ROWS)   // 1024 blocks -> 4 blocks/CU -> 16 waves/CU
#define INTEGRAL_C 1.0f

// LDS strides (floats): float4-aligned where needed, bank-spread.
#define Z_STRIDE 36    // zs[r][d]  (broadcast reads -> conflict-free anyway)
#define H_STRIDE 260   // hbuf[r][j], 260%32=4 -> rows land on distinct bank quads
#define G_STRIDE 257   // gbuf[r][j], scalar reads, 2-way max (free)

// tanh(x) = 1 - 2/(e^{2x}+1). exp overflow -> inf -> rcp -> 0 -> tanh=1;
// underflow -> 0 -> tanh=-1. Branch-free, ~4 instructions.
__device__ __forceinline__ float fast_tanh(float x) {
    const float e = __expf(2.0f * x);
    return 1.0f - 2.0f * __builtin_amdgcn_rcpf(e + 1.0f);
}

__global__ __launch_bounds__(256, 4) void ffjord_fused(
    const float* __restrict__ t,
    const float* __restrict__ z,
    const float* __restrict__ W1,
    const float* __restrict__ b1,
    const float* __restrict__ W2,
    const float* __restrict__ b2,
    float* __restrict__ f_out,
    float* __restrict__ dlogp_out)
{
    __shared__ float zs[ROWS * Z_STRIDE];      // 0.6 KB
    __shared__ float hbuf[ROWS * H_STRIDE];    // 4.1 KB
    __shared__ float gbuf[ROWS * G_STRIDE];    // 4.1 KB
    __shared__ float4 psum[256];               // 4 KB

    const int tid = threadIdx.x;
    const int row0 = blockIdx.x * ROWS;

    // ---- stage this block's 4 z rows (128 floats, coalesced) ----
    if (tid < ROWS * Dd)
        zs[(tid >> 5) * Z_STRIDE + (tid & 31)] = z[row0 * Dd + tid];

    // ---- W1 column j=tid (z-part) into registers: coalesced, independent loads ----
    float w1r[Dd];
#pragma unroll
    for (int d = 0; d < Dd; ++d)
        w1r[d] = W1[(1 + d) * Hh + tid];

    const float tval = t[0];
    const float scale = 1.0f / sqrtf(1.0f - __expf(-(INTEGRAL_C * tval * tval)));
    const float coef = -INTEGRAL_C * tval;          // f = coef*(z - scale*out)
    const float ubase = b1[tid] + tval * W1[tid];   // t*W1[0][j] + b1[j]

    // ---- c_j = sum_d W1[1+d][j] * W2[j][d]  (one-time, L2-served) ----
    float c = 0.0f;
#pragma unroll
    for (int d4 = 0; d4 < 8; ++d4) {
        const float4 w2v = *(const float4*)&W2[tid * Dd + d4 * 4];
        c += w1r[4 * d4 + 0] * w2v.x + w1r[4 * d4 + 1] * w2v.y +
             w1r[4 * d4 + 2] * w2v.z + w1r[4 * d4 + 3] * w2v.w;
    }

    __syncthreads();

    // ---- phase 1: h and trace weight for 4 rows; 4 independent accumulators ----
#pragma unroll
    for (int r = 0; r < ROWS; ++r) {
        float u0 = 0.f, u1 = 0.f, u2 = 0.f, u3 = 0.f;
#pragma unroll
        for (int d4 = 0; d4 < 8; ++d4) {
            const float4 zv = *(const float4*)&zs[r * Z_STRIDE + d4 * 4];  // broadcast
            u0 += w1r[4 * d4 + 0] * zv.x;
            u1 += w1r[4 * d4 + 1] * zv.y;
            u2 += w1r[4 * d4 + 2] * zv.z;
            u3 += w1r[4 * d4 + 3] * zv.w;
        }
        const float h = fast_tanh(ubase + ((u0 + u1) + (u2 + u3)));
        hbuf[r * H_STRIDE + tid] = h;
        gbuf[r * G_STRIDE + tid] = (1.0f - h * h) * c;
    }
    __syncthreads();

    // ---- phase 2: out = h @ W2. tid = jq*32 + r*8 + i4 ----
    {
        const int i4 = tid & 7;          // column group (4 cols)
        const int r  = (tid >> 3) & 3;   // row
        const int jq = tid >> 5;         // j-range [32*jq, 32*jq+32)
        float4 acc;
        acc.x = acc.y = acc.z = acc.w = 0.0f;
        const int j0 = jq * 32;
#pragma unroll 4
        for (int j = j0; j < j0 + 32; j += 4) {
            const float4 h4  = *(const float4*)&hbuf[r * H_STRIDE + j];
            const float4 wv0 = *(const float4*)&W2[(j + 0) * Dd + i4 * 4];
            const float4 wv1 = *(const float4*)&W2[(j + 1) * Dd + i4 * 4];
            const float4 wv2 = *(const float4*)&W2[(j + 2) * Dd + i4 * 4];
            const float4 wv3 = *(const float4*)&W2[(j + 3) * Dd + i4 * 4];
            acc.x += h4.x * wv0.x + h4.y * wv1.x + h4.z * wv2.x + h4.w * wv3.x;
            acc.y += h4.x * wv0.y + h4.y * wv1.y + h4.z * wv2.y + h4.w * wv3.y;
            acc.z += h4.x * wv0.z + h4.y * wv1.z + h4.z * wv2.z + h4.w * wv3.z;
            acc.w += h4.x * wv0.w + h4.y * wv1.w + h4.z * wv2.w + h4.w * wv3.w;
        }
        psum[tid] = acc;   // tid == jq*32 + r*8 + i4
    }

    // ---- trace reduce: wave rr owns row rr (reads gbuf, written pre-barrier) ----
    {
        const int rr = tid >> 6;        // wave id == row
        const int k  = tid & 63;
        float v = gbuf[rr * G_STRIDE + k]       + gbuf[rr * G_STRIDE + k + 64] +
                  gbuf[rr * G_STRIDE + k + 128] + gbuf[rr * G_STRIDE + k + 192];
#pragma unroll
        for (int off = 32; off > 0; off >>= 1)
            v += __shfl_xor(v, off, 64);
        if (k == 0)
            dlogp_out[row0 + rr] = INTEGRAL_C * tval * ((float)Dd - scale * v);
    }
    __syncthreads();

    // ---- combine 8 j-quarters + epilogue: f = coef*(z - scale*(out+b2)) ----
    if (tid < 32) {
        const int i4 = tid & 7;
        const int r  = tid >> 3;
        float4 s;
        s.x = s.y = s.z = s.w = 0.0f;
#pragma unroll
        for (int m = 0; m < 8; ++m) {
            const float4 p = psum[m * 32 + tid];
            s.x += p.x; s.y += p.y; s.z += p.z; s.w += p.w;
        }
        const float4 b2v = *(const float4*)&b2[i4 * 4];
        const float4 zv  = *(const float4*)&zs[r * Z_STRIDE + i4 * 4];
        float4 o;
        o.x = coef * (zv.x - scale * (s.x + b2v.x));
        o.y = coef * (zv.y - scale * (s.y + b2v.y));
        o.z = coef * (zv.z - scale * (s.z + b2v.z));
        o.w = coef * (zv.w - scale * (s.w + b2v.w));
        *(float4*)&f_out[(row0 + r) * Dd + i4 * 4] = o;
    }
}

extern "C" void kernel_launch(void* const* d_in, const int* in_sizes, int n_in,
                              void* d_out, int out_size, void* d_ws, size_t ws_size,
                              hipStream_t stream) {
    const float* t  = (const float*)d_in[0];
    const float* z  = (const float*)d_in[1];
    const float* W1 = (const float*)d_in[2];
    const float* b1 = (const float*)d_in[3];
    const float* W2 = (const float*)d_in[4];
    const float* b2 = (const float*)d_in[5];
    float* f_out = (float*)d_out;
    float* dlogp_out = f_out + Bsz * Dd;

    ffjord_fused<<<NBLK, 256, 0, stream>>>(t, z, W1, b1, W2, b2, f_out, dlogp_out);
}